// Round 13
// baseline (305.522 us; speedup 1.0000x reference)
//
#include <hip/hip_runtime.h>
#include <hip/hip_bf16.h>
#include <math.h>

typedef __attribute__((ext_vector_type(8))) short bf16x8;
typedef __attribute__((ext_vector_type(4))) float f32x4;

#define MROWS 12544      // (128+128)*49
#define CDIM 768
#define INNER 96
#define S49 49
#define NSIDE 6272       // 128*49 rows per side
#define SCALE 0.10206207261596577f
// SCALE * log2(e): Q prescale so attn can use exp2 directly
#define SCALE_EXP2 ((float)(0.10206207261596577 * 1.4426950408889634))

__device__ __forceinline__ unsigned short f2bf(float f) {
  union { float f; unsigned u; } v; v.f = f;
  unsigned u = v.u;
  return (unsigned short)((u + 0x7fffu + ((u >> 16) & 1u)) >> 16);
}
__device__ __forceinline__ float bf2f(unsigned short h) {
  union { unsigned u; float f; } v; v.u = ((unsigned)h) << 16;
  return v.f;
}
// pack two floats to bf16x2 (round-to-nearest-ish): low=a, high=b
__device__ __forceinline__ unsigned pack_bf16_rn(float a, float b) {
  union { float f; unsigned u; } ua, ub; ua.f = a; ub.f = b;
  return __builtin_amdgcn_perm(ub.u + 0x8000u, ua.u + 0x8000u, 0x07060302u);
}

// async global->LDS, 16B per lane. Dest must be wave-uniform base + lane*16.
__device__ __forceinline__ void gld16(const unsigned short* g, unsigned short* l) {
  __builtin_amdgcn_global_load_lds(
      (const __attribute__((address_space(1))) unsigned int*)(g),
      (__attribute__((address_space(3))) unsigned int*)(l), 16, 0, 0);
}

// ---------------------------------------------------------------------------
// prep_all: one kernel, three phases by block range.
// ---------------------------------------------------------------------------
__global__ __launch_bounds__(256) void prep_all(
    const float* __restrict__ fa, const float* __restrict__ fb,
    const float* __restrict__ w10, const float* __restrict__ w11,
    const float* __restrict__ w12, const float* __restrict__ w20,
    const float* __restrict__ w21, const float* __restrict__ w22,
    unsigned short* __restrict__ X,
    unsigned short* __restrict__ W1T, unsigned short* __restrict__ W2T,
    unsigned short* __restrict__ VtKpad) {
  const int t = threadIdx.x;
  int id = blockIdx.x;
  if (id < 3072) {
    __shared__ float T[64][50];
    const int z = id / 1536; id -= z * 1536;
    const int ct = id % 12, img = id / 12;
    const float* feat = z ? fb : fa;
    const float* src = feat + (size_t)img * (CDIM * S49) + (size_t)ct * 64 * S49;
    for (int idx = t; idx < 64 * S49; idx += 256) {
      int cc = idx / S49, s = idx - cc * S49;
      T[cc][s] = src[cc * S49 + s];
    }
    __syncthreads();
    unsigned short* dst = X + (size_t)(z * 128 + img) * S49 * CDIM + ct * 64;
    for (int idx = t; idx < S49 * 64; idx += 256) {
      int s = idx >> 6, cc = idx & 63;
      dst[(size_t)s * CDIM + cc] = f2bf(T[cc][s]);
    }
  } else if (id < 5016) {
    __shared__ float T[32][33];
    id -= 3072;
    const float* src;
    unsigned short* dst;
    int C, ctile, rtile;
    if (id < 1728) {
      int wdx = id / 576, tid = id - wdx * 576;
      ctile = tid % 24; rtile = tid / 24;
      src = wdx == 0 ? w10 : (wdx == 1 ? w11 : w12);
      dst = W1T + (size_t)wdx * CDIM * CDIM;
      C = CDIM;
    } else {
      id -= 1728;
      int wdx = id / 72, tid = id - wdx * 72;
      ctile = tid % 3; rtile = tid / 3;
      src = wdx == 0 ? w20 : (wdx == 1 ? w21 : w22);
      dst = W2T + (size_t)wdx * INNER * CDIM;
      C = INNER;
    }
    const int c0 = ctile * 32, r0 = rtile * 32;
    for (int idx = t; idx < 1024; idx += 256) {
      int rr = idx >> 5, cc = idx & 31;
      T[rr][cc] = src[(size_t)(r0 + rr) * C + c0 + cc];
    }
    __syncthreads();
    for (int idx = t; idx < 1024; idx += 256) {
      int rr = idx >> 5, cc = idx & 31;
      dst[(size_t)(c0 + rr) * CDIM + r0 + cc] = f2bf(T[cc][rr]);
    }
  } else {
    id -= 5016;
    ushort4* p4 = (ushort4*)VtKpad;
    const ushort4 z = make_ushort4(0, 0, 0, 0);
#pragma unroll
    for (int i = 0; i < 32; i++)
      p4[(size_t)id * 8192 + i * 256 + t] = z;
  }
}

// ---------------------------------------------------------------------------
// gemm1b4: H[wdx] = relu(X @ W1[wdx]). 128x128 tile, BK=64, gld16 staging.
// 512 threads / 8 waves, wave tile 32x64. MFMA operands SWAPPED (A=W rows,
// B=X rows) so D's register quad indexes n -> epilogue packs 4 consecutive
// bf16 per uint2 store (8 stores/thread vs 32 scalar b16 in R12).
// ---------------------------------------------------------------------------
__global__ __launch_bounds__(512) void gemm1b4(const unsigned short* __restrict__ X,
                                               const unsigned short* __restrict__ W1T,
                                               unsigned short* __restrict__ H,
                                               int wbase, int hsel) {
  __shared__ __align__(16) unsigned short As[128 * 64];
  __shared__ __align__(16) unsigned short Bs[128 * 64];
  const int t = threadIdx.x;
  const int lane = t & 63, w = t >> 6;
  const int lr = lane & 15, lq = lane >> 4;
  const int wm = w & 3;          // m quarter (32 rows)
  const int wn = w >> 2;         // n half (64 cols)
  const int m0 = blockIdx.y * 128, n0 = blockIdx.x * 128;
  const int wdx = blockIdx.z + wbase;
  const unsigned short* W1w = W1T + (size_t)wdx * CDIM * CDIM;
  unsigned short* Hw = H + (hsel ? (size_t)wdx * MROWS * CDIM : 0);
  const f32x4 z4 = {0.f, 0.f, 0.f, 0.f};
  f32x4 acc[2][4] = {{z4, z4, z4, z4}, {z4, z4, z4, z4}};

  for (int k0 = 0; k0 < CDIM; k0 += 64) {
    __syncthreads();
#pragma unroll
    for (int j = 0; j < 2; j++) {
      int idx = t + j * 512;               // 0..1023
      int row = idx >> 3, col = (idx & 7) * 8;
      gld16(X + (size_t)(m0 + row) * CDIM + k0 + col, As + idx * 8);
      gld16(W1w + (size_t)(n0 + row) * CDIM + k0 + col, Bs + idx * 8);
    }
    __syncthreads();
#pragma unroll
    for (int ks = 0; ks < 2; ks++) {
      bf16x8 a[2], b[4];
#pragma unroll
      for (int mt = 0; mt < 2; mt++)
        a[mt] = *(const bf16x8*)(As + (wm * 32 + mt * 16 + lr) * 64 + ks * 32 + lq * 8);
#pragma unroll
      for (int nt = 0; nt < 4; nt++)
        b[nt] = *(const bf16x8*)(Bs + (wn * 64 + nt * 16 + lr) * 64 + ks * 32 + lq * 8);
#pragma unroll
      for (int mt = 0; mt < 2; mt++)
#pragma unroll
        for (int nt = 0; nt < 4; nt++)
          acc[mt][nt] = __builtin_amdgcn_mfma_f32_16x16x32_bf16(b[nt], a[mt], acc[mt][nt], 0, 0, 0);
    }
  }
  // D layout (operands swapped): col=lr -> m, row=lq*4+r -> n (reg-contiguous)
#pragma unroll
  for (int mt = 0; mt < 2; mt++)
#pragma unroll
    for (int nt = 0; nt < 4; nt++) {
      int m = m0 + wm * 32 + mt * 16 + lr;
      int n = n0 + wn * 64 + nt * 16 + lq * 4;
      float v0 = fmaxf(acc[mt][nt][0], 0.f), v1 = fmaxf(acc[mt][nt][1], 0.f);
      float v2 = fmaxf(acc[mt][nt][2], 0.f), v3 = fmaxf(acc[mt][nt][3], 0.f);
      uint2 pk = make_uint2(pack_bf16_rn(v0, v1), pack_bf16_rn(v2, v3));
      *(uint2*)(Hw + (size_t)m * CDIM + n) = pk;
    }
}

// ---------------------------------------------------------------------------
// gemm2b3: O = H[wdx] @ W2[wdx]. 64x96 tile. Epilogue mode = wdx.
// ---------------------------------------------------------------------------
#define LDK 72
__global__ __launch_bounds__(256) void gemm2b3(const unsigned short* __restrict__ H,
                                               const unsigned short* __restrict__ W2T,
                                               unsigned short* __restrict__ QKV,
                                               unsigned short* __restrict__ Kpad,
                                               unsigned short* __restrict__ Vt,
                                               float* __restrict__ vnorm,
                                               int wbase, int hsel) {
  __shared__ __align__(16) unsigned short As[64 * LDK];
  __shared__ __align__(16) unsigned short Bs[96 * LDK];
  const int t = threadIdx.x;
  const int lane = t & 63, w = t >> 6;
  const int lr = lane & 15, lq = lane >> 4;
  const int m0 = blockIdx.x * 64;
  const int wdx = blockIdx.y + wbase;
  const unsigned short* Hw = H + (hsel ? (size_t)wdx * MROWS * CDIM : 0);
  const unsigned short* W2w = W2T + (size_t)wdx * INNER * CDIM;
  const f32x4 z4 = {0.f, 0.f, 0.f, 0.f};
  f32x4 acc[6] = {z4, z4, z4, z4, z4, z4};

  for (int k0 = 0; k0 < CDIM; k0 += 64) {
    __syncthreads();
    for (int c = t; c < 512; c += 256) {
      int r = c >> 3, kc = (c & 7) * 8;
      *(uint4*)(As + r * LDK + kc) = *(const uint4*)(Hw + (size_t)(m0 + r) * CDIM + k0 + kc);
    }
    for (int c = t; c < 768; c += 256) {
      int r = c >> 3, kc = (c & 7) * 8;
      *(uint4*)(Bs + r * LDK + kc) = *(const uint4*)(W2w + (size_t)r * CDIM + k0 + kc);
    }
    __syncthreads();
#pragma unroll
    for (int kk = 0; kk < 2; kk++) {
      bf16x8 a = *(const bf16x8*)(As + (w * 16 + lr) * LDK + kk * 32 + lq * 8);
#pragma unroll
      for (int nt = 0; nt < 6; nt++) {
        bf16x8 b = *(const bf16x8*)(Bs + (nt * 16 + lr) * LDK + kk * 32 + lq * 8);
        acc[nt] = __builtin_amdgcn_mfma_f32_16x16x32_bf16(a, b, acc[nt], 0, 0, 0);
      }
    }
  }
  float nsq[4] = {0.f, 0.f, 0.f, 0.f};
#pragma unroll
  for (int nt = 0; nt < 6; nt++)
#pragma unroll
    for (int r = 0; r < 4; r++) {
      int m = m0 + w * 16 + lq * 4 + r;
      int e = nt * 16 + lr;
      float v = acc[nt][r];
      int img = m / 49, s = m - img * 49;
      if (wdx == 0) {
        QKV[(size_t)m * INNER + e] = f2bf(v * SCALE_EXP2);
      } else if (wdx == 1) {
        Kpad[(size_t)(img * 64 + s) * INNER + e] = f2bf(v);
      } else {
        QKV[(size_t)(2 * MROWS + m) * INNER + e] = f2bf(v);
        Vt[(size_t)img * (INNER * 64) + e * 64 + s] = f2bf(v);
        nsq[r] += v * v;
      }
    }
  if (wdx == 2) {
#pragma unroll
    for (int r = 0; r < 4; r++) {
      float p = nsq[r];
      p += __shfl_xor(p, 1, 16);
      p += __shfl_xor(p, 2, 16);
      p += __shfl_xor(p, 4, 16);
      p += __shfl_xor(p, 8, 16);
      if (lr == 0) vnorm[m0 + w * 16 + lq * 4 + r] = sqrtf(p);
    }
  }
}

// ---------------------------------------------------------------------------
// attn10: attn8 (best measured: 32 q/wave, Q+refV regs, dbuf async K+Vt)
// with fg=8 (1568 blocks of half length). R12 analysis: 784 equal blocks on
// 512 residency slots = 1.53 rounds -> ~30% makespan overhead from the
// 272-block tail. 1568 half-length blocks pack to ~1.53T with a 32-block
// tail. Q/refV restage now amortized over 8 f (still cheap).
// ---------------------------------------------------------------------------
#define LVS 72    // Ps stride (36 words: 2-way max)
__global__ __launch_bounds__(256) void attn10(const unsigned short* __restrict__ Qp,
                                              const unsigned short* __restrict__ Kpad,
                                              const unsigned short* __restrict__ V,
                                              const unsigned short* __restrict__ Vt,
                                              const float* __restrict__ vnorm,
                                              float* __restrict__ cosbuf) {
  __shared__ __align__(16) unsigned short KsD[2][64 * INNER];  // 24 KB
  __shared__ __align__(16) unsigned short VtD[2][INNER * 64];  // 24 KB
  __shared__ __align__(16) unsigned short Ps[4][32 * LVS];     // 18.4 KB

  const int t = threadIdx.x;
  const int lane = t & 63, w = t >> 6;
  const int lr = lane & 15, lq = lane >> 4;
  const f32x4 z4 = {0.f, 0.f, 0.f, 0.f};

  int bx = blockIdx.x;
  const int dir = bx / 784; bx -= dir * 784;   // 784 = 49 chunks * 16 fgroups
  const int chunk = bx >> 4, fg = bx & 15;
  const int r0 = chunk * 128;
  const int qbase = dir * NSIDE;

  // ---- staging maps (lds offset is wave-uniform base + lane*16 by constr.)
  int goK[3], goV[3], lo[3];
#pragma unroll
  for (int j = 0; j < 3; j++) {
    int l = (w * 3 + j) * 64 + lane;          // chunk id 0..767
    lo[j] = l * 8;
    int rK = l / 12, scK = l - rK * 12;
    int ccK = scK - ((rK >> 1) & 7); if (ccK < 0) ccK += 12;
    goK[j] = rK * INNER + ccK * 8;
    int rV = l >> 3, scV = l & 7;
    int ccV = (scV - (rV & 7)) & 7;
    goV[j] = rV * 64 + ccV * 8;
  }
  // ---- swizzled read offsets (within-row chunk position)
  int rdK[3], rdV[2];
#pragma unroll
  for (int ks = 0; ks < 3; ks++) {
    int sc = (ks * 4 + lq + ((lr >> 1) & 7)) % 12;
    rdK[ks] = lr * INNER + sc * 8;            // + kt*16*INNER
  }
#pragma unroll
  for (int ks = 0; ks < 2; ks++) {
    int sc = (ks * 4 + lq + (lr & 7)) & 7;
    rdV[ks] = lr * 64 + sc * 8;               // + et*16*64
  }

  // ---- Q fragments into registers (B-operand layout: n=lr, k=ks*32+lq*8)
  bf16x8 qf[2][3];
#pragma unroll
  for (int qt = 0; qt < 2; qt++) {
    const int qrow = qbase + r0 + w * 32 + qt * 16 + lr;
#pragma unroll
    for (int ks = 0; ks < 3; ks++)
      qf[qt][ks] = *(const bf16x8*)(Qp + (size_t)qrow * INNER + ks * 32 + lq * 8);
  }
  // ---- reference V + 1/vnorm into registers (PV D-layout: e=et*16+lq*4+r)
  float rv[2][6][4], invvn[2];
#pragma unroll
  for (int qt = 0; qt < 2; qt++) {
    const int qrow = qbase + r0 + w * 32 + qt * 16 + lr;
    invvn[qt] = 1.f / fmaxf(vnorm[qrow], 1e-8f);
#pragma unroll
    for (int et = 0; et < 6; et++) {
      ushort4 u = *(const ushort4*)(V + (size_t)qrow * INNER + et * 16 + lq * 4);
      rv[qt][et][0] = bf2f(u.x); rv[qt][et][1] = bf2f(u.y);
      rv[qt][et][2] = bf2f(u.z); rv[qt][et][3] = bf2f(u.w);
    }
  }

  unsigned short* Pw = &Ps[w][0];
  const int kimg0 = (dir == 0 ? 128 : 0) + fg * 8;
  // ---- prologue: prefetch f-slot 0 into buffer 0
  {
    const unsigned short* kg = Kpad + (size_t)kimg0 * (64 * INNER);
    const unsigned short* vg = Vt + (size_t)kimg0 * (INNER * 64);
#pragma unroll
    for (int j = 0; j < 3; j++) {
      gld16(kg + goK[j], &KsD[0][0] + lo[j]);
      gld16(vg + goV[j], &VtD[0][0] + lo[j]);
    }
  }
  for (int fi = 0; fi < 8; fi++) {
    const int f = fg * 8 + fi;
    __syncthreads();   // drains prefetch into buf fi&1 (vmcnt(0) before barrier)
    // ---- issue prefetch for f+1 into the alternate buffer (async, 0 VGPRs)
    if (fi < 7) {
      const unsigned short* kg = Kpad + (size_t)(kimg0 + fi + 1) * (64 * INNER);
      const unsigned short* vg = Vt + (size_t)(kimg0 + fi + 1) * (INNER * 64);
      unsigned short* kd = &KsD[1 - (fi & 1)][0];
      unsigned short* vd = &VtD[1 - (fi & 1)][0];
#pragma unroll
      for (int j = 0; j < 3; j++) {
        gld16(kg + goK[j], kd + lo[j]);
        gld16(vg + goV[j], vd + lo[j]);
      }
    }
    const unsigned short* KsC = &KsD[fi & 1][0];
    const unsigned short* VtC = &VtD[fi & 1][0];
    // ---- S^T = K @ Q^T : each a-fragment feeds BOTH q-tiles
    f32x4 s4[2][4] = {{z4, z4, z4, z4}, {z4, z4, z4, z4}};
#pragma unroll
    for (int ks = 0; ks < 3; ks++) {
#pragma unroll
      for (int kt = 0; kt < 4; kt++) {
        bf16x8 a = *(const bf16x8*)(KsC + kt * (16 * INNER) + rdK[ks]);
        s4[0][kt] = __builtin_amdgcn_mfma_f32_16x16x32_bf16(a, qf[0][ks], s4[0][kt], 0, 0, 0);
        s4[1][kt] = __builtin_amdgcn_mfma_f32_16x16x32_bf16(a, qf[1][ks], s4[1][kt], 0, 0, 0);
      }
    }
    // ---- P[q][k] = exp2(S^T), packed pairs
#pragma unroll
    for (int qt = 0; qt < 2; qt++)
#pragma unroll
      for (int kt = 0; kt < 4; kt++) {
        float e0 = __builtin_exp2f(s4[qt][kt][0]);
        float e1 = __builtin_exp2f(s4[qt][kt][1]);
        float e2 = __builtin_exp2f(s4[qt][kt][2]);
        float e3 = __builtin_exp2f(s4[qt][kt][3]);
        uint2 pk = make_uint2(pack_bf16_rn(e0, e1), pack_bf16_rn(e2, e3));
        *(uint2*)(Pw + (qt * 16 + lr) * LVS + kt * 16 + lq * 4) = pk;
      }
    // ---- aligned^T[e][q] = Vt @ P^T (wave-private Ps; a-fragment reused 2x)
    f32x4 pv[2][6] = {{z4, z4, z4, z4, z4, z4}, {z4, z4, z4, z4, z4, z4}};
#pragma unroll
    for (int ks = 0; ks < 2; ks++) {
      bf16x8 b0 = *(const bf16x8*)(Pw + (0 * 16 + lr) * LVS + ks * 32 + lq * 8);
      bf16x8 b1 = *(const bf16x8*)(Pw + (1 * 16 + lr) * LVS + ks * 32 + lq * 8);
#pragma unroll
      for (int et = 0; et < 6; et++) {
        bf16x8 a = *(const bf16x8*)(VtC + et * (16 * 64) + rdV[ks]);
        pv[0][et] = __builtin_amdgcn_mfma_f32_16x16x32_bf16(a, b0, pv[0][et], 0, 0, 0);
        pv[1][et] = __builtin_amdgcn_mfma_f32_16x16x32_bf16(a, b1, pv[1][et], 0, 0, 0);
      }
    }
    // ---- cosine epilogue per q-tile: lane owns query q=lr
#pragma unroll
    for (int qt = 0; qt < 2; qt++) {
      float d = 0.f, nn = 0.f;
#pragma unroll
      for (int et = 0; et < 6; et++)
#pragma unroll
        for (int r = 0; r < 4; r++) {
          float al = pv[qt][et][r];
          d += al * rv[qt][et][r];
          nn += al * al;
        }
      d += __shfl_xor(d, 16, 64);  d += __shfl_xor(d, 32, 64);
      nn += __shfl_xor(nn, 16, 64); nn += __shfl_xor(nn, 32, 64);
      if (lane < 16) {
        float cv = d * __frsqrt_rn(fmaxf(nn, 1e-40f)) * invvn[qt];
        cosbuf[(size_t)(dir * 128 + f) * NSIDE + r0 + w * 32 + qt * 16 + lr] = cv;
      }
    }
  }
}

// ---------------------------------------------------------------------------
// reduce_out: out[bb*128+aa] = (sum_q cos0[bb][aa*49+q] + cos1[aa][bb*49+q])/49
// ---------------------------------------------------------------------------
__global__ __launch_bounds__(256) void reduce_out(const float* __restrict__ cosbuf,
                                                  float* __restrict__ out) {
  const int t = threadIdx.x, lane = t & 63, wv = t >> 6;
  const int pair = blockIdx.x * 4 + wv;
  const int bb = pair >> 7, aa = pair & 127;
  float v = 0.f;
  if (lane < S49) {
    v  = cosbuf[(size_t)bb * NSIDE + aa * S49 + lane];
    v += cosbuf[(size_t)(128 + aa) * NSIDE + bb * S49 + lane];
  }
  for (int m = 1; m < 64; m <<= 1) v += __shfl_xor(v, m, 64);
  if (lane == 0) out[pair] = v * (1.f / 49.f);
}

// ---------------------------------------------------------------------------
extern "C" void kernel_launch(void* const* d_in, const int* in_sizes, int n_in,
                              void* d_out, int out_size, void* d_ws, size_t ws_size,
                              hipStream_t stream) {
  const float* fa  = (const float*)d_in[0];
  const float* fb  = (const float*)d_in[1];
  const float* W1[3] = {(const float*)d_in[2], (const float*)d_in[4], (const float*)d_in[6]};
  const float* W2[3] = {(const float*)d_in[3], (const float*)d_in[5], (const float*)d_in[7]};
  float* out = (float*)d_out;

  unsigned short* p = (unsigned short*)d_ws;
  unsigned short* Xbf = p;                 p += (size_t)MROWS * CDIM;      // 19.3 MB
  unsigned short* W1T = p;                 p += (size_t)3 * CDIM * CDIM;   // 3.5 MB
  unsigned short* W2T = p;                 p += (size_t)3 * INNER * CDIM;  // 0.44 MB
  unsigned short* QKV = p;                 p += (size_t)3 * MROWS * INNER; // 7.2 MB
  unsigned short* Vt  = p;                 p += (size_t)256 * INNER * 64;  // 3.1 MB
  unsigned short* Kpad = p;                p += (size_t)256 * 64 * INNER;  // 3.1 MB (adjacent to Vt!)
  float* vnorm = (float*)p;                p += (size_t)MROWS * 2;         // 50 KB
  float* cosbuf = (float*)p;               p += (size_t)256 * NSIDE * 2;   // 6.4 MB
  unsigned short* H = p;                   p += (size_t)3 * MROWS * CDIM;  // 57.8 MB (batched)
  const size_t need_batched = (size_t)(p - (unsigned short*)d_ws) * 2;
  const int batched = ws_size >= need_batched;

  prep_all<<<dim3(5112), 256, 0, stream>>>(fa, fb, W1[0], W1[1], W1[2],
                                           W2[0], W2[1], W2[2],
                                           Xbf, W1T, W2T, Vt /* VtKpad span */);
  if (batched) {
    gemm1b4<<<dim3(CDIM / 128, MROWS / 128, 3), 512, 0, stream>>>(Xbf, W1T, H, 0, 1);
    gemm2b3<<<dim3(MROWS / 64, 3), 256, 0, stream>>>(H, W2T, QKV, Kpad, Vt, vnorm, 0, 1);
  } else {
    for (int wdx = 0; wdx < 3; wdx++) {
      gemm1b4<<<dim3(CDIM / 128, MROWS / 128, 1), 512, 0, stream>>>(Xbf, W1T, H, wdx, 0);
      gemm2b3<<<dim3(MROWS / 64, 1), 256, 0, stream>>>(H, W2T, QKV, Kpad, Vt, vnorm, wdx, 0);
    }
  }
  attn10<<<dim3(2 * 784), 256, 0, stream>>>(
      QKV, Kpad, QKV + (size_t)2 * MROWS * INNER, Vt, vnorm, cosbuf);
  reduce_out<<<dim3(4096), 256, 0, stream>>>(cosbuf, out);
}